// Round 7
// baseline (169.782 us; speedup 1.0000x reference)
//
#include <hip/hip_runtime.h>
#include <math.h>

#define BS 8
#define NPTS 16384
#define C 32
#define K 256
#define KNNK 16
#define NBINS 512
#define BINW 0.00025f
#define CAP 2048
#define NSPL 64          // point-splits per graph in k_logits
#define R0SQ 0.16f       // fixed candidate radius 0.4^2 (exact R_f ~0.19; checked)

typedef float f32x4 __attribute__((ext_vector_type(4)));
typedef __bf16 bf16x8 __attribute__((ext_vector_type(8)));
union U16x8 { int4 i; bf16x8 v; unsigned short u[8]; };

// ---------------------------------------------------------------------------
// Phase 1: MFMA logit GEMM + exp + weighted position accumulation.
// Split-bf16: L = A_lo*B_hi + A_hi*B_lo + A_hi*B_hi (fp32 MFMA accum);
// pooling head (W_pool) cancels in the per-graph softmax, never computed.
// Extras this round: per-block pos-sum (for the c' reference point used by
// the KNN candidate filter) and zeroing of hist/counters (ws is poisoned).
// ---------------------------------------------------------------------------
__global__ __launch_bounds__(256, 2) void k_logits(
    const float* __restrict__ f, const float* __restrict__ pos,
    const float* __restrict__ Wr, float* __restrict__ partials,
    float* __restrict__ possums, unsigned* __restrict__ hist,
    unsigned* __restrict__ cand_cnt, unsigned* __restrict__ ovf,
    unsigned* __restrict__ maxd2) {
  int b = blockIdx.x >> 6;          // 64 blocks per graph
  int r = blockIdx.x & 63;
  int pbase = b * NPTS + r * 256;
  int t = threadIdx.x;
  int w = t >> 6, lane = t & 63;
  int h = w & 1, nh = w >> 1;
  int quad = lane >> 4, col = lane & 15;

  if (r == 0) {                      // zero per-graph scratch (stream-ordered
    hist[b * NBINS + t] = 0;         // before k_prep's atomics)
    hist[b * NBINS + 256 + t] = 0;
    if (t == 0) { cand_cnt[b] = 0; ovf[b] = 0; maxd2[b] = 0; }
  }

  __shared__ float4 posLDS[256];
  __shared__ float4 fm[2][256];

  // stage pos chunk (256 pts x 12 B) -> padded float4 via LDS repack
  float* rawf = (float*)&fm[0][0];
  if (t < 192) ((float4*)rawf)[t] = ((const float4*)(pos + (size_t)pbase * 3))[t];
  __syncthreads();
  float4 myp = make_float4(rawf[t * 3], rawf[t * 3 + 1], rawf[t * 3 + 2], 0.f);
  __syncthreads();
  posLDS[t] = myp;

  // B fragments for this wave's kp-half (8 tiles), direct fp32 load + split.
  U16x8 Bh[8], Bl[8];
#pragma unroll
  for (int jt = 0; jt < 8; jt++) {
    int tile = h * 8 + jt;
#pragma unroll
    for (int j = 0; j < 8; j++) {
      float v = Wr[(quad * 8 + j) * K + tile * 16 + col];
      unsigned u = __float_as_uint(v);
      unsigned hb = u >> 16;
      float hf = __uint_as_float(hb << 16);
      unsigned lb = __float_as_uint(v - hf) >> 16;
      Bh[jt].u[j] = (unsigned short)hb;
      Bl[jt].u[j] = (unsigned short)lb;
    }
  }
  float acce[8], accx[8], accy[8], accz[8];
#pragma unroll
  for (int jt = 0; jt < 8; jt++) { acce[jt] = 0.f; accx[jt] = 0.f; accy[jt] = 0.f; accz[jt] = 0.f; }

#pragma unroll 1
  for (int nt = nh * 8; nt < nh * 8 + 8; nt++) {
    const float* fb = f + ((size_t)(pbase + nt * 16 + col)) * C + quad * 8;
    float4 a0 = *(const float4*)fb;
    float4 a1 = *(const float4*)(fb + 4);
    float av[8] = {a0.x, a0.y, a0.z, a0.w, a1.x, a1.y, a1.z, a1.w};
    U16x8 Ah, Al;
#pragma unroll
    for (int j = 0; j < 8; j++) {
      unsigned u = __float_as_uint(av[j]);
      unsigned hb = u >> 16;
      float hf = __uint_as_float(hb << 16);
      unsigned lb = __float_as_uint(av[j] - hf) >> 16;
      Ah.u[j] = (unsigned short)hb;
      Al.u[j] = (unsigned short)lb;
    }
    float4 pr0 = posLDS[nt * 16 + quad * 4 + 0];
    float4 pr1 = posLDS[nt * 16 + quad * 4 + 1];
    float4 pr2 = posLDS[nt * 16 + quad * 4 + 2];
    float4 pr3 = posLDS[nt * 16 + quad * 4 + 3];
#pragma unroll
    for (int jt = 0; jt < 8; jt++) {
      f32x4 d = {0.f, 0.f, 0.f, 0.f};
      d = __builtin_amdgcn_mfma_f32_16x16x32_bf16(Al.v, Bh[jt].v, d, 0, 0, 0);
      d = __builtin_amdgcn_mfma_f32_16x16x32_bf16(Ah.v, Bl[jt].v, d, 0, 0, 0);
      d = __builtin_amdgcn_mfma_f32_16x16x32_bf16(Ah.v, Bh[jt].v, d, 0, 0, 0);
      // C/D layout: col=lane&15 (kp), row=quad*4+reg (pt)  [m89-verified]
      float e0 = __expf(d[0]), e1 = __expf(d[1]), e2 = __expf(d[2]), e3 = __expf(d[3]);
      acce[jt] += (e0 + e1) + (e2 + e3);
      accx[jt] += e0 * pr0.x + e1 * pr1.x + e2 * pr2.x + e3 * pr3.x;
      accy[jt] += e0 * pr0.y + e1 * pr1.y + e2 * pr2.y + e3 * pr3.y;
      accz[jt] += e0 * pr0.z + e1 * pr1.z + e2 * pr2.z + e3 * pr3.z;
    }
  }

  // reduce across quads (lane bits 4,5); kp slot = h*128 + jt*16 + (lane&15)
#pragma unroll
  for (int jt = 0; jt < 8; jt++) {
    acce[jt] += __shfl_xor(acce[jt], 16); acce[jt] += __shfl_xor(acce[jt], 32);
    accx[jt] += __shfl_xor(accx[jt], 16); accx[jt] += __shfl_xor(accx[jt], 32);
    accy[jt] += __shfl_xor(accy[jt], 16); accy[jt] += __shfl_xor(accy[jt], 32);
    accz[jt] += __shfl_xor(accz[jt], 16); accz[jt] += __shfl_xor(accz[jt], 32);
  }
  __syncthreads();   // fm[0] was aliased as pos staging; all reads done
  if (lane < 16) {
#pragma unroll
    for (int jt = 0; jt < 8; jt++)
      fm[nh][h * 128 + jt * 16 + lane] = make_float4(acce[jt], accx[jt], accy[jt], accz[jt]);
  }
  __syncthreads();
  float4 v0 = fm[0][t], v1 = fm[1][t];
  float4* po = (float4*)partials;
  po[(size_t)blockIdx.x * 256 + t] =
      make_float4(v0.x + v1.x, v0.y + v1.y, v0.z + v1.z, v0.w + v1.w);

  // per-block pos sum (for c' reference point)
  float psx = myp.x, psy = myp.y, psz = myp.z;
#pragma unroll
  for (int off = 32; off; off >>= 1) {
    psx += __shfl_xor(psx, off, 64);
    psy += __shfl_xor(psy, off, 64);
    psz += __shfl_xor(psz, off, 64);
  }
  __shared__ float pw[4][3];
  if (lane == 0) { pw[w][0] = psx; pw[w][1] = psy; pw[w][2] = psz; }
  __syncthreads();
  if (t == 0) {
    ((float4*)possums)[blockIdx.x] = make_float4(
        pw[0][0] + pw[1][0] + pw[2][0] + pw[3][0],
        pw[0][1] + pw[1][1] + pw[2][1] + pw[3][1],
        pw[0][2] + pw[1][2] + pw[2][2] + pw[3][2], 0.f);
  }
}

// ---------------------------------------------------------------------------
// Phase 2 (64 blocks, 8 per graph): distributed version of round-6's k_graph
// (which was 8-blocks-only and single-CU bandwidth-bound at 45 us).
//   - c' = point-cloud mean from possums (valid triangle-ineq reference)
//   - merge partials -> 32 keypoints/block; atomicMax d2(kp, c')
//   - histogram + fixed-R0 candidate compaction of a 2048-pt slice
// ~60 device-scope atomics per graph total (no contention).
// ---------------------------------------------------------------------------
__global__ __launch_bounds__(256) void k_prep(
    const float* __restrict__ pos, const float* __restrict__ partials,
    const float* __restrict__ possums, float* __restrict__ keypoints,
    unsigned* __restrict__ hist, unsigned* __restrict__ cand_cnt,
    unsigned* __restrict__ ovf, unsigned* __restrict__ maxd2,
    int* __restrict__ cand) {
  int g = blockIdx.x;
  int b = g >> 3, s = g & 7;
  int t = threadIdx.x, lane = t & 63;

  __shared__ float sd[8][32][4];
  __shared__ float dm[32];
  __shared__ float cs[3];

  // c' (every wave computes redundantly; L2-broadcast reads)
  {
    float4 v = ((const float4*)possums)[b * NSPL + lane];
    float sx = v.x, sy = v.y, sz = v.z;
#pragma unroll
    for (int off = 32; off; off >>= 1) {
      sx += __shfl_xor(sx, off, 64);
      sy += __shfl_xor(sy, off, 64);
      sz += __shfl_xor(sz, off, 64);
    }
    if (t == 0) {
      cs[0] = sx * (1.f / NPTS); cs[1] = sy * (1.f / NPTS); cs[2] = sz * (1.f / NPTS);
    }
  }

  // merge partials for this block's 32 keypoints
  int kl = t & 31, seg = t >> 5;
  const float4* po = (const float4*)partials;
  {
    float sl = 0.f, sx = 0.f, sy = 0.f, sz = 0.f;
#pragma unroll 2
    for (int j = 0; j < 8; j++) {
      float4 v = po[(size_t)(b * NSPL + seg * 8 + j) * 256 + s * 32 + kl];
      sl += v.x; sx += v.y; sy += v.z; sz += v.w;
    }
    sd[seg][kl][0] = sl; sd[seg][kl][1] = sx;
    sd[seg][kl][2] = sy; sd[seg][kl][3] = sz;
  }
  __syncthreads();
  float cx = cs[0], cy = cs[1], cz = cs[2];
  if (t < 32) {
    float L = 0.f, X = 0.f, Y = 0.f, Z = 0.f;
#pragma unroll
    for (int i = 0; i < 8; i++) {
      L += sd[i][t][0]; X += sd[i][t][1]; Y += sd[i][t][2]; Z += sd[i][t][3];
    }
    float inv = 1.f / L;
    float kx = X * inv, ky = Y * inv, kz = Z * inv;
    float* kpp = keypoints + (size_t)(b * K + s * 32 + t) * 3;
    kpp[0] = kx; kpp[1] = ky; kpp[2] = kz;
    float dx = kx - cx, dy = ky - cy, dz = kz - cz;
    dm[t] = dx * dx + dy * dy + dz * dz;
  }
  __syncthreads();
  if (t == 0) {
    float m = 0.f;
#pragma unroll
    for (int i = 0; i < 32; i++) m = fmaxf(m, dm[i]);
    atomicMax(&maxd2[b], __float_as_uint(m));   // d2>=0: uint order == float order
  }

  // histogram + fixed-radius compact of this block's 2048-pt slice
#pragma unroll 2
  for (int i = 0; i < 8; i++) {
    int pl = s * 2048 + i * 256 + t;
    const float* pp = pos + (size_t)(b * NPTS + pl) * 3;
    float dx = pp[0] - cx, dy = pp[1] - cy, dz = pp[2] - cz;
    float d2 = dx * dx + dy * dy + dz * dz;
    int bin = (int)(d2 * (1.0f / BINW));
    if (bin < NBINS - 1) atomicAdd(&hist[b * NBINS + bin], 1u);
    if (d2 <= R0SQ) {
      unsigned u = atomicAdd(&cand_cnt[b], 1u);
      if (u < CAP) cand[b * CAP + u] = pl;
      else ovf[b] = 1u;
    }
  }
}

// ---------------------------------------------------------------------------
// Phase 3 (256 blocks, 32/graph, 8 kp each): exact radius from hist
// (T >= d16(c'); R_f = T + 2*max d(kp,c') -- triangle inequality, so the
// fixed-R0 candidate buffer is a provable superset when R_f <= R0), exact
// top-16 over LDS candidates, then gather 16 f rows, mean, 32x32 linear.
// Full-scan fallback if the filter degenerates -- always correct.
// ---------------------------------------------------------------------------
__global__ __launch_bounds__(256) void k_extract(
    const float* __restrict__ f, const float* __restrict__ pos,
    const float* __restrict__ keypoints, const unsigned* __restrict__ hist,
    const unsigned* __restrict__ cand_cnt, const unsigned* __restrict__ ovf,
    const unsigned* __restrict__ maxd2, const int* __restrict__ cand,
    const float* __restrict__ We, float* __restrict__ out) {
  int b = blockIdx.x >> 5, kg = blockIdx.x & 31;
  int t = threadIdx.x;

  __shared__ float4 cnd[CAP];      // 32 KiB
  __shared__ unsigned histL[NBINS];
  __shared__ int knnL[8][KNNK];
  __shared__ float P[8][C + 1];
  __shared__ int shv[1];

  unsigned craw = cand_cnt[b];
  unsigned o = ovf[b];
  int cnt = (int)(craw < (unsigned)CAP ? craw : (unsigned)CAP);
  histL[t] = hist[b * NBINS + t];
  histL[t + 256] = hist[b * NBINS + 256 + t];
  if (!o) {
    for (int j = t; j < cnt; j += 256) {
      int pl = cand[b * CAP + j];
      const float* pp = pos + (size_t)(b * NPTS + pl) * 3;
      cnd[j] = make_float4(pp[0], pp[1], pp[2], __int_as_float(pl));
    }
  }
  __syncthreads();
  if (t == 0) {
    unsigned cum = 0; float T2 = -1.f;
#pragma unroll 8
    for (int i = 0; i < NBINS - 1; i++) {
      cum += histL[i];
      if (cum >= KNNK) { T2 = (i + 1) * BINW; break; }
    }
    int valid = 0;
    if (T2 > 0.f && !o && craw <= (unsigned)CAP) {
      float rf = sqrtf(T2) + 2.f * sqrtf(__uint_as_float(maxd2[b]));
      if (rf * rf <= R0SQ) valid = 1;
    }
    shv[0] = valid;
  }
  __syncthreads();

  if (t < 8) {
    int kp = kg * 8 + t;
    const float* kpp = keypoints + (size_t)(b * K + kp) * 3;
    float kx = kpp[0], ky = kpp[1], kz = kpp[2];
    float dd[KNNK]; int ii[KNNK];
#pragma unroll
    for (int j = 0; j < KNNK; j++) { dd[j] = 1e30f; ii[j] = 0; }
    float mx = 1e30f;
    if (shv[0]) {
      for (int j = 0; j < cnt; j++) {
        float4 q = cnd[j];
        float dx = kx - q.x, dy = ky - q.y, dz = kz - q.z;
        float d2 = dx * dx + dy * dy + dz * dz;
        if (d2 < mx) {
          int sm = 0; float bv = dd[0];
#pragma unroll
          for (int s = 1; s < KNNK; s++) if (dd[s] > bv) { bv = dd[s]; sm = s; }
#pragma unroll
          for (int s = 0; s < KNNK; s++) if (s == sm) { dd[s] = d2; ii[s] = __float_as_int(q.w); }
          mx = dd[0];
#pragma unroll
          for (int s = 1; s < KNNK; s++) mx = fmaxf(mx, dd[s]);
        }
      }
    } else {
      // correctness fallback: full scan (never triggers on sane data)
      for (int j = 0; j < NPTS; j++) {
        const float* pp = pos + (size_t)(b * NPTS + j) * 3;
        float dx = kx - pp[0], dy = ky - pp[1], dz = kz - pp[2];
        float d2 = dx * dx + dy * dy + dz * dz;
        if (d2 < mx) {
          int sm = 0; float bv = dd[0];
#pragma unroll
          for (int s = 1; s < KNNK; s++) if (dd[s] > bv) { bv = dd[s]; sm = s; }
#pragma unroll
          for (int s = 0; s < KNNK; s++) if (s == sm) { dd[s] = d2; ii[s] = j; }
          mx = dd[0];
#pragma unroll
          for (int s = 1; s < KNNK; s++) mx = fmaxf(mx, dd[s]);
        }
      }
    }
#pragma unroll
    for (int j = 0; j < KNNK; j++) knnL[t][j] = ii[j];
  }
  __syncthreads();

  // gather 16 neighbor feature rows, mean, 32x32 linear
  int kp8 = t >> 5, c = t & 31;
  float s = 0.f;
#pragma unroll
  for (int j = 0; j < KNNK; j++) {
    int pl = knnL[kp8][j];
    s += f[((size_t)(b * NPTS + pl)) * C + c];
  }
  P[kp8][c] = s * (1.f / KNNK);
  __syncthreads();
  float r = 0.f;
#pragma unroll
  for (int cc = 0; cc < C; cc++) r += P[kp8][cc] * We[cc * C + c];
  out[((size_t)(b * K + kg * 8 + kp8)) * C + c] = r;
}

extern "C" void kernel_launch(void* const* d_in, const int* in_sizes, int n_in,
                              void* d_out, int out_size, void* d_ws, size_t ws_size,
                              hipStream_t stream) {
  const float* f   = (const float*)d_in[0];
  const float* pos = (const float*)d_in[1];
  // d_in[2] = W_pool: mathematically unused (bias cancels in segment softmax)
  const float* Wr  = (const float*)d_in[3];
  const float* We  = (const float*)d_in[4];
  float* out = (float*)d_out;

  char* ws = (char*)d_ws;
  float*    partials  = (float*)(ws + 0);          // [512][256][4] f32 = 2 MiB
  float*    possums   = (float*)(ws + 2097152);    // [512] float4     = 8 KiB
  float*    keypoints = (float*)(ws + 2105344);    // [2048][3] f32    = 24 KiB
  unsigned* hist      = (unsigned*)(ws + 2129920); // [8][512] u32     = 16 KiB
  int*      cand      = (int*)(ws + 2146304);      // [8][2048] i32    = 64 KiB
  unsigned* cand_cnt  = (unsigned*)(ws + 2211840); // [8] u32
  unsigned* ovf       = (unsigned*)(ws + 2211872); // [8] u32
  unsigned* maxd2     = (unsigned*)(ws + 2211904); // [8] u32

  k_logits <<<dim3(BS * NSPL), dim3(256), 0, stream>>>(
      f, pos, Wr, partials, possums, hist, cand_cnt, ovf, maxd2);
  k_prep   <<<dim3(BS * 8),    dim3(256), 0, stream>>>(
      pos, partials, possums, keypoints, hist, cand_cnt, ovf, maxd2, cand);
  k_extract<<<dim3(256),       dim3(256), 0, stream>>>(
      f, pos, keypoints, hist, cand_cnt, ovf, maxd2, cand, We, out);
}

// Round 8
// 137.826 us; speedup vs baseline: 1.2319x; 1.2319x over previous
//
#include <hip/hip_runtime.h>
#include <math.h>

#define BS 8
#define NPTS 16384
#define C 32
#define K 256
#define KNNK 16
#define NBINS 512
#define BINW 0.00025f
#define CAP 2048
#define CAPL 512         // LDS candidate cap in k_extract (8 slots/lane)
#define NSPL 64          // point-splits per graph in k_logits
#define R0SQ 0.16f       // fixed candidate radius 0.4^2 (exact R_f ~0.21; checked)

typedef float f32x4 __attribute__((ext_vector_type(4)));
typedef __bf16 bf16x8 __attribute__((ext_vector_type(8)));
union U16x8 { int4 i; bf16x8 v; unsigned short u[8]; };

// ---------------------------------------------------------------------------
// Phase 1: MFMA logit GEMM + exp + weighted position accumulation.
// Split-bf16: L = A_lo*B_hi + A_hi*B_lo + A_hi*B_hi (fp32 MFMA accum);
// pooling head (W_pool) cancels in the per-graph softmax, never computed.
// Also emits per-block pos-sums (c' reference point) and zeroes scratch.
// ---------------------------------------------------------------------------
__global__ __launch_bounds__(256, 2) void k_logits(
    const float* __restrict__ f, const float* __restrict__ pos,
    const float* __restrict__ Wr, float* __restrict__ partials,
    float* __restrict__ possums, unsigned* __restrict__ hist,
    unsigned* __restrict__ cand_cnt, unsigned* __restrict__ ovf,
    unsigned* __restrict__ maxd2) {
  int b = blockIdx.x >> 6;          // 64 blocks per graph
  int r = blockIdx.x & 63;
  int pbase = b * NPTS + r * 256;
  int t = threadIdx.x;
  int w = t >> 6, lane = t & 63;
  int h = w & 1, nh = w >> 1;
  int quad = lane >> 4, col = lane & 15;

  if (r == 0) {                      // zero per-graph scratch (stream-ordered
    hist[b * NBINS + t] = 0;         // before k_prep's atomics)
    hist[b * NBINS + 256 + t] = 0;
    if (t == 0) { cand_cnt[b] = 0; ovf[b] = 0; maxd2[b] = 0; }
  }

  __shared__ float4 posLDS[256];
  __shared__ float4 fm[2][256];

  // stage pos chunk (256 pts x 12 B) -> padded float4 via LDS repack
  float* rawf = (float*)&fm[0][0];
  if (t < 192) ((float4*)rawf)[t] = ((const float4*)(pos + (size_t)pbase * 3))[t];
  __syncthreads();
  float4 myp = make_float4(rawf[t * 3], rawf[t * 3 + 1], rawf[t * 3 + 2], 0.f);
  __syncthreads();
  posLDS[t] = myp;

  // B fragments for this wave's kp-half (8 tiles), direct fp32 load + split.
  U16x8 Bh[8], Bl[8];
#pragma unroll
  for (int jt = 0; jt < 8; jt++) {
    int tile = h * 8 + jt;
#pragma unroll
    for (int j = 0; j < 8; j++) {
      float v = Wr[(quad * 8 + j) * K + tile * 16 + col];
      unsigned u = __float_as_uint(v);
      unsigned hb = u >> 16;
      float hf = __uint_as_float(hb << 16);
      unsigned lb = __float_as_uint(v - hf) >> 16;
      Bh[jt].u[j] = (unsigned short)hb;
      Bl[jt].u[j] = (unsigned short)lb;
    }
  }
  float acce[8], accx[8], accy[8], accz[8];
#pragma unroll
  for (int jt = 0; jt < 8; jt++) { acce[jt] = 0.f; accx[jt] = 0.f; accy[jt] = 0.f; accz[jt] = 0.f; }

#pragma unroll 1
  for (int nt = nh * 8; nt < nh * 8 + 8; nt++) {
    const float* fb = f + ((size_t)(pbase + nt * 16 + col)) * C + quad * 8;
    float4 a0 = *(const float4*)fb;
    float4 a1 = *(const float4*)(fb + 4);
    float av[8] = {a0.x, a0.y, a0.z, a0.w, a1.x, a1.y, a1.z, a1.w};
    U16x8 Ah, Al;
#pragma unroll
    for (int j = 0; j < 8; j++) {
      unsigned u = __float_as_uint(av[j]);
      unsigned hb = u >> 16;
      float hf = __uint_as_float(hb << 16);
      unsigned lb = __float_as_uint(av[j] - hf) >> 16;
      Ah.u[j] = (unsigned short)hb;
      Al.u[j] = (unsigned short)lb;
    }
    float4 pr0 = posLDS[nt * 16 + quad * 4 + 0];
    float4 pr1 = posLDS[nt * 16 + quad * 4 + 1];
    float4 pr2 = posLDS[nt * 16 + quad * 4 + 2];
    float4 pr3 = posLDS[nt * 16 + quad * 4 + 3];
#pragma unroll
    for (int jt = 0; jt < 8; jt++) {
      f32x4 d = {0.f, 0.f, 0.f, 0.f};
      d = __builtin_amdgcn_mfma_f32_16x16x32_bf16(Al.v, Bh[jt].v, d, 0, 0, 0);
      d = __builtin_amdgcn_mfma_f32_16x16x32_bf16(Ah.v, Bl[jt].v, d, 0, 0, 0);
      d = __builtin_amdgcn_mfma_f32_16x16x32_bf16(Ah.v, Bh[jt].v, d, 0, 0, 0);
      // C/D layout: col=lane&15 (kp), row=quad*4+reg (pt)  [m89-verified]
      float e0 = __expf(d[0]), e1 = __expf(d[1]), e2 = __expf(d[2]), e3 = __expf(d[3]);
      acce[jt] += (e0 + e1) + (e2 + e3);
      accx[jt] += e0 * pr0.x + e1 * pr1.x + e2 * pr2.x + e3 * pr3.x;
      accy[jt] += e0 * pr0.y + e1 * pr1.y + e2 * pr2.y + e3 * pr3.y;
      accz[jt] += e0 * pr0.z + e1 * pr1.z + e2 * pr2.z + e3 * pr3.z;
    }
  }

  // reduce across quads (lane bits 4,5); kp slot = h*128 + jt*16 + (lane&15)
#pragma unroll
  for (int jt = 0; jt < 8; jt++) {
    acce[jt] += __shfl_xor(acce[jt], 16); acce[jt] += __shfl_xor(acce[jt], 32);
    accx[jt] += __shfl_xor(accx[jt], 16); accx[jt] += __shfl_xor(accx[jt], 32);
    accy[jt] += __shfl_xor(accy[jt], 16); accy[jt] += __shfl_xor(accy[jt], 32);
    accz[jt] += __shfl_xor(accz[jt], 16); accz[jt] += __shfl_xor(accz[jt], 32);
  }
  __syncthreads();   // fm[0] was aliased as pos staging; all reads done
  if (lane < 16) {
#pragma unroll
    for (int jt = 0; jt < 8; jt++)
      fm[nh][h * 128 + jt * 16 + lane] = make_float4(acce[jt], accx[jt], accy[jt], accz[jt]);
  }
  __syncthreads();
  float4 v0 = fm[0][t], v1 = fm[1][t];
  float4* po = (float4*)partials;
  po[(size_t)blockIdx.x * 256 + t] =
      make_float4(v0.x + v1.x, v0.y + v1.y, v0.z + v1.z, v0.w + v1.w);

  // per-block pos sum (for c' reference point)
  float psx = myp.x, psy = myp.y, psz = myp.z;
#pragma unroll
  for (int off = 32; off; off >>= 1) {
    psx += __shfl_xor(psx, off, 64);
    psy += __shfl_xor(psy, off, 64);
    psz += __shfl_xor(psz, off, 64);
  }
  __shared__ float pw[4][3];
  if (lane == 0) { pw[w][0] = psx; pw[w][1] = psy; pw[w][2] = psz; }
  __syncthreads();
  if (t == 0) {
    ((float4*)possums)[blockIdx.x] = make_float4(
        pw[0][0] + pw[1][0] + pw[2][0] + pw[3][0],
        pw[0][1] + pw[1][1] + pw[2][1] + pw[3][1],
        pw[0][2] + pw[1][2] + pw[2][2] + pw[3][2], 0.f);
  }
}

// ---------------------------------------------------------------------------
// Phase 2 (64 blocks, 8 per graph): c' = point-cloud mean; merge partials ->
// 32 keypoints/block; atomicMax d2(kp,c'); histogram + fixed-R0 candidate
// compaction of a 2048-pt slice. ~60 device-scope atomics per graph.
// ---------------------------------------------------------------------------
__global__ __launch_bounds__(256) void k_prep(
    const float* __restrict__ pos, const float* __restrict__ partials,
    const float* __restrict__ possums, float* __restrict__ keypoints,
    unsigned* __restrict__ hist, unsigned* __restrict__ cand_cnt,
    unsigned* __restrict__ ovf, unsigned* __restrict__ maxd2,
    int* __restrict__ cand) {
  int g = blockIdx.x;
  int b = g >> 3, s = g & 7;
  int t = threadIdx.x, lane = t & 63;

  __shared__ float sd[8][32][4];
  __shared__ float dm[32];
  __shared__ float cs[3];

  // c' (wave 0 computes; L2-broadcast reads)
  if (t < 64) {
    float4 v = ((const float4*)possums)[b * NSPL + lane];
    float sx = v.x, sy = v.y, sz = v.z;
#pragma unroll
    for (int off = 32; off; off >>= 1) {
      sx += __shfl_xor(sx, off, 64);
      sy += __shfl_xor(sy, off, 64);
      sz += __shfl_xor(sz, off, 64);
    }
    if (t == 0) {
      cs[0] = sx * (1.f / NPTS); cs[1] = sy * (1.f / NPTS); cs[2] = sz * (1.f / NPTS);
    }
  }

  // merge partials for this block's 32 keypoints
  int kl = t & 31, seg = t >> 5;
  const float4* po = (const float4*)partials;
  {
    float sl = 0.f, sx = 0.f, sy = 0.f, sz = 0.f;
#pragma unroll 2
    for (int j = 0; j < 8; j++) {
      float4 v = po[(size_t)(b * NSPL + seg * 8 + j) * 256 + s * 32 + kl];
      sl += v.x; sx += v.y; sy += v.z; sz += v.w;
    }
    sd[seg][kl][0] = sl; sd[seg][kl][1] = sx;
    sd[seg][kl][2] = sy; sd[seg][kl][3] = sz;
  }
  __syncthreads();
  float cx = cs[0], cy = cs[1], cz = cs[2];
  if (t < 32) {
    float L = 0.f, X = 0.f, Y = 0.f, Z = 0.f;
#pragma unroll
    for (int i = 0; i < 8; i++) {
      L += sd[i][t][0]; X += sd[i][t][1]; Y += sd[i][t][2]; Z += sd[i][t][3];
    }
    float inv = 1.f / L;
    float kx = X * inv, ky = Y * inv, kz = Z * inv;
    float* kpp = keypoints + (size_t)(b * K + s * 32 + t) * 3;
    kpp[0] = kx; kpp[1] = ky; kpp[2] = kz;
    float dx = kx - cx, dy = ky - cy, dz = kz - cz;
    dm[t] = dx * dx + dy * dy + dz * dz;
  }
  __syncthreads();
  if (t == 0) {
    float m = 0.f;
#pragma unroll
    for (int i = 0; i < 32; i++) m = fmaxf(m, dm[i]);
    atomicMax(&maxd2[b], __float_as_uint(m));   // d2>=0: uint order == float order
  }

  // histogram + fixed-radius compact of this block's 2048-pt slice
#pragma unroll 2
  for (int i = 0; i < 8; i++) {
    int pl = s * 2048 + i * 256 + t;
    const float* pp = pos + (size_t)(b * NPTS + pl) * 3;
    float dx = pp[0] - cx, dy = pp[1] - cy, dz = pp[2] - cz;
    float d2 = dx * dx + dy * dy + dz * dz;
    int bin = (int)(d2 * (1.0f / BINW));
    if (bin < NBINS - 1) atomicAdd(&hist[b * NBINS + bin], 1u);
    if (d2 <= R0SQ) {
      unsigned u = atomicAdd(&cand_cnt[b], 1u);
      if (u < CAP) cand[b * CAP + u] = pl;
      else ovf[b] = 1u;
    }
  }
}

// ---------------------------------------------------------------------------
// Phase 3 (256 blocks, 32/graph, 8 kp each): exact radius from hist
// (T >= d16(c'); R_f = T + 2*max d(kp,c') -- triangle inequality, so the
// fixed-R0 candidate list is a provable top-16 superset when R_f <= R0 and
// craw <= CAPL). KNN via wave-parallel iterative-min: each wave owns 2 kp;
// 64 lanes hold <=8 packed (d2|slot) u64 candidates; 16 rounds of
// {local min over 8 regs -> 6-step shuffle-xor u64 min -> owner invalidates}.
// Replaces round-7's 8-lane insertion sort (59us: wave executed the 120-cyc
// serial insertion block nearly every iteration via exec-mask divergence).
// Then gather 16 f rows, mean, 32x32 linear. Full-scan fallback if the
// filter degenerates -- always correct.
// ---------------------------------------------------------------------------
__global__ __launch_bounds__(256) void k_extract(
    const float* __restrict__ f, const float* __restrict__ pos,
    const float* __restrict__ keypoints, const unsigned* __restrict__ hist,
    const unsigned* __restrict__ cand_cnt, const unsigned* __restrict__ ovf,
    const unsigned* __restrict__ maxd2, const int* __restrict__ cand,
    const float* __restrict__ We, float* __restrict__ out) {
  int b = blockIdx.x >> 5, kg = blockIdx.x & 31;
  int t = threadIdx.x;
  int wv = t >> 6, lane = t & 63;

  __shared__ float4 cnd[CAPL];     // 8 KiB
  __shared__ unsigned histL[NBINS];
  __shared__ int knnL[8][KNNK];
  __shared__ float P[8][C + 1];
  __shared__ int shv[1];

  unsigned craw = cand_cnt[b];
  unsigned o = ovf[b];
  int cnt = (int)(craw < (unsigned)CAPL ? craw : (unsigned)CAPL);
  histL[t] = hist[b * NBINS + t];
  histL[t + 256] = hist[b * NBINS + 256 + t];
  for (int j = t; j < cnt; j += 256) {
    int pl = cand[b * CAP + j];
    const float* pp = pos + (size_t)(b * NPTS + pl) * 3;
    cnd[j] = make_float4(pp[0], pp[1], pp[2], __int_as_float(pl));
  }
  if (t == 0) shv[0] = 0;
  __syncthreads();
  if (t == 0) {
    unsigned cum = 0; float T2 = -1.f;
    for (int i = 0; i < NBINS - 1; i++) {
      cum += histL[i];
      if (cum >= KNNK) { T2 = (i + 1) * BINW; break; }
    }
    int valid = 0;
    if (T2 > 0.f && !o && craw <= (unsigned)CAPL) {
      float rf = sqrtf(T2) + 2.f * sqrtf(__uint_as_float(maxd2[b]));
      if (rf * rf <= R0SQ) valid = 1;
    }
    shv[0] = valid;
  }
  __syncthreads();

  if (shv[0]) {
    // wave-parallel iterative-min top-16; wave wv handles kp pair
#pragma unroll 1
    for (int half = 0; half < 2; half++) {
      int kl = wv * 2 + half;
      const float* kpp = keypoints + (size_t)(b * K + kg * 8 + kl) * 3;
      float kx = kpp[0], ky = kpp[1], kz = kpp[2];
      unsigned long long ld[8];
#pragma unroll
      for (int q = 0; q < 8; q++) {
        int slot = lane + 64 * q;
        if (slot < cnt) {
          float4 v = cnd[slot];
          float dx = kx - v.x, dy = ky - v.y, dz = kz - v.z;
          float d2 = dx * dx + dy * dy + dz * dz;
          ld[q] = ((unsigned long long)__float_as_uint(d2) << 32) | (unsigned)slot;
        } else ld[q] = ~0ull;
      }
#pragma unroll 1
      for (int it = 0; it < KNNK; it++) {
        unsigned long long m = ld[0];
#pragma unroll
        for (int q = 1; q < 8; q++) m = (ld[q] < m) ? ld[q] : m;
#pragma unroll
        for (int off = 1; off < 64; off <<= 1) {
          unsigned long long mo =
              (unsigned long long)__shfl_xor((long long)m, off, 64);
          m = (mo < m) ? mo : m;
        }
#pragma unroll
        for (int q = 0; q < 8; q++) if (ld[q] == m) ld[q] = ~0ull;
        if (lane == 0) {
          int slot = (int)(m & 0xFFFFFFFFu);
          knnL[kl][it] = __float_as_int(cnd[slot].w);
        }
      }
    }
  } else if (t < 8) {
    // correctness fallback: full scan (never triggers on sane data)
    int kp = kg * 8 + t;
    const float* kpp = keypoints + (size_t)(b * K + kp) * 3;
    float kx = kpp[0], ky = kpp[1], kz = kpp[2];
    float dd[KNNK]; int ii[KNNK];
#pragma unroll
    for (int j = 0; j < KNNK; j++) { dd[j] = 1e30f; ii[j] = 0; }
    float mx = 1e30f;
    for (int j = 0; j < NPTS; j++) {
      const float* pp = pos + (size_t)(b * NPTS + j) * 3;
      float dx = kx - pp[0], dy = ky - pp[1], dz = kz - pp[2];
      float d2 = dx * dx + dy * dy + dz * dz;
      if (d2 < mx) {
        int sm = 0; float bv = dd[0];
#pragma unroll
        for (int s = 1; s < KNNK; s++) if (dd[s] > bv) { bv = dd[s]; sm = s; }
#pragma unroll
        for (int s = 0; s < KNNK; s++) if (s == sm) { dd[s] = d2; ii[s] = j; }
        mx = dd[0];
#pragma unroll
        for (int s = 1; s < KNNK; s++) mx = fmaxf(mx, dd[s]);
      }
    }
#pragma unroll
    for (int j = 0; j < KNNK; j++) knnL[t][j] = ii[j];
  }
  __syncthreads();

  // gather 16 neighbor feature rows, mean, 32x32 linear
  int kp8 = t >> 5, c = t & 31;
  float s = 0.f;
#pragma unroll
  for (int j = 0; j < KNNK; j++) {
    int pl = knnL[kp8][j];
    s += f[((size_t)(b * NPTS + pl)) * C + c];
  }
  P[kp8][c] = s * (1.f / KNNK);
  __syncthreads();
  float r = 0.f;
#pragma unroll
  for (int cc = 0; cc < C; cc++) r += P[kp8][cc] * We[cc * C + c];
  out[((size_t)(b * K + kg * 8 + kp8)) * C + c] = r;
}

extern "C" void kernel_launch(void* const* d_in, const int* in_sizes, int n_in,
                              void* d_out, int out_size, void* d_ws, size_t ws_size,
                              hipStream_t stream) {
  const float* f   = (const float*)d_in[0];
  const float* pos = (const float*)d_in[1];
  // d_in[2] = W_pool: mathematically unused (bias cancels in segment softmax)
  const float* Wr  = (const float*)d_in[3];
  const float* We  = (const float*)d_in[4];
  float* out = (float*)d_out;

  char* ws = (char*)d_ws;
  float*    partials  = (float*)(ws + 0);          // [512][256][4] f32 = 2 MiB
  float*    possums   = (float*)(ws + 2097152);    // [512] float4     = 8 KiB
  float*    keypoints = (float*)(ws + 2105344);    // [2048][3] f32    = 24 KiB
  unsigned* hist      = (unsigned*)(ws + 2129920); // [8][512] u32     = 16 KiB
  int*      cand      = (int*)(ws + 2146304);      // [8][2048] i32    = 64 KiB
  unsigned* cand_cnt  = (unsigned*)(ws + 2211840); // [8] u32
  unsigned* ovf       = (unsigned*)(ws + 2211872); // [8] u32
  unsigned* maxd2     = (unsigned*)(ws + 2211904); // [8] u32

  k_logits <<<dim3(BS * NSPL), dim3(256), 0, stream>>>(
      f, pos, Wr, partials, possums, hist, cand_cnt, ovf, maxd2);
  k_prep   <<<dim3(BS * 8),    dim3(256), 0, stream>>>(
      pos, partials, possums, keypoints, hist, cand_cnt, ovf, maxd2, cand);
  k_extract<<<dim3(256),       dim3(256), 0, stream>>>(
      f, pos, keypoints, hist, cand_cnt, ovf, maxd2, cand, We, out);
}